// Round 9
// baseline (83.866 us; speedup 1.0000x reference)
//
#include <hip/hip_runtime.h>
#include <hip/hip_bf16.h>
#include <math.h>

#define TOK_TOTAL 16384
#define D_MODEL   2048
#define NEXP      64
#define BM        64               // tokens per gemm block
#define KC        32               // k per LDS chunk
#define KHALF     1024             // split-K: half of K per block
#define NCH       (KHALF / KC)     // 32
#define PAD       40               // shorts per LDS row (80 B)
#define TAU       1e-3f

#define IDX_OFF   (TOK_TOTAL * NEXP)
#define LOSS_OFF  (IDX_OFF + TOK_TOTAL * 2)

// ws layout (floats): p1 [16384*64] | cntp [256*64] | rep_cnt [1] | rep_list [16384]
#define WS_CNT    (TOK_TOTAL * NEXP)
#define WS_RCNT   (WS_CNT + TOK_TOTAL)
#define WS_RLIST  (WS_RCNT + 1)

typedef __attribute__((ext_vector_type(8))) short short8_t;
typedef __attribute__((ext_vector_type(4))) float f32x4;

// ---------------- K1: split-bf16 MFMA GEMM, split-K x2, 4 blocks/CU -----------
__global__ __launch_bounds__(256, 4)
void router_gemm(const float* __restrict__ x, const float* __restrict__ W,
                 float* __restrict__ p0, float* __restrict__ p1,
                 int* __restrict__ rep_cnt)
{
    __shared__ __align__(16) short lds[2][4][BM][PAD];   // 40960 B -> 4 blocks/CU

    const int t  = threadIdx.x;
    const int w  = t >> 6;
    const int l  = t & 63;
    const int kh = blockIdx.x & 1;
    const long tok0 = (long)(blockIdx.x >> 1) * BM;
    const long kb0  = (long)kh * KHALF;

    if (blockIdx.x == 0 && t == 0) *rep_cnt = 0;   // replaces hipMemsetAsync node

    const int sr = t >> 3;          // staging row base 0..31 (rows sr, sr+32)
    const int sc = (t & 7) * 4;     // staging k column (elems, 0..28)

    f32x4 acc[4];
    #pragma unroll
    for (int nt = 0; nt < 4; ++nt) acc[nt] = (f32x4){0.f, 0.f, 0.f, 0.f};

    float4 xr[2], wr[2];

    auto LOADCH = [&](int ic) {
        const long k0 = kb0 + (long)ic * KC;
        #pragma unroll
        for (int p = 0; p < 2; ++p) {
            xr[p] = *(const float4*)(x + (tok0 + sr + 32 * p) * D_MODEL + k0 + sc);
            wr[p] = *(const float4*)(W + (long)(sr + 32 * p) * D_MODEL + k0 + sc);
        }
    };

    auto STORECH = [&](int buf) {
        #pragma unroll
        for (int p = 0; p < 2; ++p) {
            const int row = sr + 32 * p;
            const float fx[4] = {xr[p].x, xr[p].y, xr[p].z, xr[p].w};
            const float fw[4] = {wr[p].x, wr[p].y, wr[p].z, wr[p].w};
            short xh[4], xl[4], wh[4], wl[4];
            #pragma unroll
            for (int j = 0; j < 4; ++j) {
                __hip_bfloat16 h = __float2bfloat16(fx[j]);
                xh[j] = __builtin_bit_cast(short, h);
                xl[j] = __builtin_bit_cast(short, __float2bfloat16(fx[j] - __bfloat162float(h)));
                __hip_bfloat16 g = __float2bfloat16(fw[j]);
                wh[j] = __builtin_bit_cast(short, g);
                wl[j] = __builtin_bit_cast(short, __float2bfloat16(fw[j] - __bfloat162float(g)));
            }
            *(short4*)(&lds[buf][0][row][sc]) = make_short4(xh[0], xh[1], xh[2], xh[3]);
            *(short4*)(&lds[buf][1][row][sc]) = make_short4(xl[0], xl[1], xl[2], xl[3]);
            *(short4*)(&lds[buf][2][row][sc]) = make_short4(wh[0], wh[1], wh[2], wh[3]);
            *(short4*)(&lds[buf][3][row][sc]) = make_short4(wl[0], wl[1], wl[2], wl[3]);
        }
    };

    auto COMPUTE = [&](int buf) {
        const int arow = w * 16 + (l & 15);
        const int ke   = (l >> 4) * 8;
        short8_t ah = *(const short8_t*)(&lds[buf][0][arow][ke]);
        short8_t al = *(const short8_t*)(&lds[buf][1][arow][ke]);
        #pragma unroll
        for (int nt = 0; nt < 4; ++nt) {
            const int brow = nt * 16 + (l & 15);
            short8_t bh = *(const short8_t*)(&lds[buf][2][brow][ke]);
            short8_t bl = *(const short8_t*)(&lds[buf][3][brow][ke]);
            acc[nt] = __builtin_amdgcn_mfma_f32_16x16x32_bf16(ah, bl, acc[nt], 0, 0, 0);
            acc[nt] = __builtin_amdgcn_mfma_f32_16x16x32_bf16(al, bh, acc[nt], 0, 0, 0);
            acc[nt] = __builtin_amdgcn_mfma_f32_16x16x32_bf16(ah, bh, acc[nt], 0, 0, 0);
        }
    };

    LOADCH(0);
    STORECH(0);
    __syncthreads();

    for (int ic = 0; ic < NCH; ++ic) {
        const int buf = ic & 1;
        const bool pre = (ic + 1 < NCH);
        if (pre) LOADCH(ic + 1);     // in flight during COMPUTE
        COMPUTE(buf);
        if (pre) STORECH(buf ^ 1);   // other buffer: no reader this iteration
        __syncthreads();             // one barrier per chunk
    }

    float* dst = kh ? p1 : p0;
    #pragma unroll
    for (int nt = 0; nt < 4; ++nt)
        #pragma unroll
        for (int r = 0; r < 4; ++r)
            dst[(tok0 + w * 16 + (l >> 4) * 4 + r) * NEXP + nt * 16 + (l & 15)] = acc[nt][r];
}

// -------- K2: all-register combine: top-3 via shfl merge ----------------------
__global__ __launch_bounds__(256, 1)
void router_combine(const float* __restrict__ p0, const float* __restrict__ p1,
                    float* __restrict__ out, float* __restrict__ cntp,
                    int* __restrict__ rep_cnt, int* __restrict__ rep_list)
{
    __shared__ float4 s_ig[64];      // (i0, i1, g0, g1) per token
    const int t = threadIdx.x;
    const int r = t >> 2, q = t & 3;
    const long tok0 = (long)blockIdx.x * 64;
    const long tok  = tok0 + r;

    // my 16-expert quarter, fully in registers
    float v[16];
    {
        const float4* a4 = (const float4*)(p0 + tok * NEXP) + q * 4;
        const float4* b4 = (const float4*)(p1 + tok * NEXP) + q * 4;
        #pragma unroll
        for (int j = 0; j < 4; ++j) {
            float4 a = a4[j], b = b4[j];
            v[j*4+0] = a.x + b.x; v[j*4+1] = a.y + b.y;
            v[j*4+2] = a.z + b.z; v[j*4+3] = a.w + b.w;
        }
    }

    // local top-3 (indices for top-2), ascending e => ties keep lower index
    float b0 = -1e30f, b1 = -1e30f, b2 = -1e30f;
    int i0 = 0, i1 = 0;
    const int ebase = q * 16;
    #pragma unroll
    for (int j = 0; j < 16; ++j) {
        float xv = v[j]; int e = ebase + j;
        if (xv > b0)      { b2 = b1; b1 = b0; i1 = i0; b0 = xv; i0 = e; }
        else if (xv > b1) { b2 = b1; b1 = xv; i1 = e; }
        else if (xv > b2) { b2 = xv; }
    }

    // merge across the 4 lanes of this token (xor 1, then xor 2)
    #pragma unroll
    for (int d = 1; d <= 2; d <<= 1) {
        float ob0 = __shfl_xor(b0, d, 64), ob1 = __shfl_xor(b1, d, 64), ob2 = __shfl_xor(b2, d, 64);
        int   oi0 = __shfl_xor(i0, d, 64), oi1 = __shfl_xor(i1, d, 64);
        bool a0w = (b0 > ob0) || (b0 == ob0 && i0 < oi0);
        float nb0 = a0w ? b0 : ob0;  int ni0 = a0w ? i0 : oi0;
        float ca  = a0w ? b1 : ob1;  int cia = a0w ? i1 : oi1;   // winner's 2nd
        float cb  = a0w ? ob0 : b0;  int cib = a0w ? oi0 : i0;   // loser's 1st
        float wa2 = a0w ? b2 : ob2;                              // winner's 3rd
        float lb1 = a0w ? ob1 : b1;                              // loser's 2nd
        bool w1 = (ca > cb) || (ca == cb && cia < cib);
        float nb1 = w1 ? ca : cb;  int ni1 = w1 ? cia : cib;
        float nb2 = w1 ? fmaxf(wa2, cb) : fmaxf(ca, lb1);
        b0 = nb0; i0 = ni0; b1 = nb1; i1 = ni1; b2 = nb2;
    }

    float ex = __expf(b1 - b0);
    float g0 = 1.f / (1.f + ex);
    float g1 = ex * g0;

    // gates quarter from registers
    {
        float* orow = out + tok * NEXP + ebase;
        #pragma unroll
        for (int j4 = 0; j4 < 4; ++j4) {
            float gv[4];
            #pragma unroll
            for (int j = 0; j < 4; ++j) {
                int e = ebase + j4 * 4 + j;
                gv[j] = (e == i0) ? g0 : ((e == i1) ? g1 : 0.f);
            }
            *(float4*)(orow + j4 * 4) = make_float4(gv[0], gv[1], gv[2], gv[3]);
        }
    }

    if (q == 0) {
        out[IDX_OFF + 2 * tok]     = (float)i0;
        out[IDX_OFF + 2 * tok + 1] = (float)i1;
        s_ig[r] = make_float4((float)i0, (float)i1, g0, g1);
        if ((b0 - b1 < TAU) || (b1 - b2 < TAU)) {
            int p = atomicAdd(rep_cnt, 1);
            rep_list[p] = (int)tok;
        }
    }
    __syncthreads();

    if (t < 64) {
        float c = 0.f;
        for (int tt = 0; tt < 64; ++tt) {
            float4 gg = s_ig[tt];
            if ((int)gg.x == t) c += gg.z;
            if ((int)gg.y == t) c += gg.w;
        }
        cntp[blockIdx.x * NEXP + t] = c;
    }
}

// -------- K3: fused tail: block 0 = loss; blocks 1.. = fp64 index repair ------
__global__ __launch_bounds__(256, 1)
void router_tail(const float* __restrict__ x, const float* __restrict__ W,
                 float* __restrict__ out, const float* __restrict__ cntp,
                 const int* __restrict__ rep_cnt, const int* __restrict__ rep_list)
{
    const int t = threadIdx.x;

    if (blockIdx.x == 0) {
        // ---- load-balance loss ----
        __shared__ double red[4][NEXP];
        const int e = t & 63, p = t >> 6;
        double s = 0.0;
        for (int b = 0; b < 64; ++b)
            s += (double)cntp[(p * 64 + b) * NEXP + e];
        red[p][e] = s;
        __syncthreads();
        if (t == 0) {
            double sc[NEXP], tot = 0.0;
            for (int i = 0; i < NEXP; ++i) {
                sc[i] = red[0][i] + red[1][i] + red[2][i] + red[3][i];
                tot += sc[i];
            }
            double loss = 0.0;
            for (int i = 0; i < NEXP; ++i) {
                double d = sc[i] / tot * (double)NEXP - 1.0;
                loss += d * d;
            }
            out[LOSS_OFF] = (float)(loss / NEXP);
        }
        return;
    }

    // ---- fp64 repair: one block per flagged token (grid-stride) ----
    __shared__ double red[4][NEXP];
    const int nf = *rep_cnt;
    const int e = t & 63, part = t >> 6;
    for (int i = (int)blockIdx.x - 1; i < nf; i += (int)gridDim.x - 1) {
        const long tok = rep_list[i];
        const float* xr = x + tok * D_MODEL;
        const float* wr = W + (long)e * D_MODEL;
        const int k0 = part * 512;
        double s = 0.0;
        for (int kk = 0; kk < 512; kk += 4) {
            float4 xv = *(const float4*)(xr + k0 + kk);
            float4 wv = *(const float4*)(wr + k0 + kk);
            s = fma((double)xv.x, (double)wv.x, s);
            s = fma((double)xv.y, (double)wv.y, s);
            s = fma((double)xv.z, (double)wv.z, s);
            s = fma((double)xv.w, (double)wv.w, s);
        }
        red[part][e] = s;
        __syncthreads();
        if (t == 0) {
            double best = -1e300, sec = -1e300;
            int bi = 0, si = 0;
            for (int ee = 0; ee < NEXP; ++ee) {
                double vv = red[0][ee] + red[1][ee] + red[2][ee] + red[3][ee];
                if (vv > best)     { sec = best; si = bi; best = vv; bi = ee; }
                else if (vv > sec) { sec = vv; si = ee; }
            }
            out[IDX_OFF + 2 * tok]     = (float)bi;
            out[IDX_OFF + 2 * tok + 1] = (float)si;
        }
        __syncthreads();
    }
}

extern "C" void kernel_launch(void* const* d_in, const int* in_sizes, int n_in,
                              void* d_out, int out_size, void* d_ws, size_t ws_size,
                              hipStream_t stream)
{
    const float* x = (const float*)d_in[0];
    const float* W = (const float*)d_in[1];
    float* out  = (float*)d_out;
    float* ws   = (float*)d_ws;        // ~4.33 MB used
    float* p0   = out;                 // kh=0 partial parks in gates region
    float* p1   = ws;                  // kh=1 partial
    float* cntp = ws + WS_CNT;
    int*   rep_cnt  = (int*)(ws + WS_RCNT);
    int*   rep_list = (int*)(ws + WS_RLIST);

    router_gemm   <<<(TOK_TOTAL / BM) * 2, 256, 0, stream>>>(x, W, p0, p1, rep_cnt);
    router_combine<<<TOK_TOTAL / 64, 256, 0, stream>>>(p0, p1, out, cntp, rep_cnt, rep_list);
    router_tail   <<<257, 256, 0, stream>>>(x, W, out, cntp, rep_cnt, rep_list);
}

// Round 10
// 83.730 us; speedup vs baseline: 1.0016x; 1.0016x over previous
//
#include <hip/hip_runtime.h>
#include <hip/hip_bf16.h>
#include <math.h>

#define TOK_TOTAL 16384
#define D_MODEL   2048
#define NEXP      64
#define KQ        1024             // split-K: half of K per wave
#define NCHQ      (KQ / 32)        // 32 chunks of K=32
#define TAU       1e-3f

#define IDX_OFF   (TOK_TOTAL * NEXP)
#define LOSS_OFF  (IDX_OFF + TOK_TOTAL * 2)

// ws layout (floats):
// p1 [16384*64] | WH8 [256KB] | WL8 [256KB] | cntp [256*64] | rep_cnt | rep_list
#define WS_WH     (TOK_TOTAL * NEXP)         // 1048576
#define WS_WL     (WS_WH + 65536)
#define WS_CNTP   (WS_WL + 65536)
#define WS_RCNT   (WS_CNTP + 16384)
#define WS_RLIST  (WS_RCNT + 1)

typedef __attribute__((ext_vector_type(8))) short short8_t;
typedef __attribute__((ext_vector_type(4))) float f32x4;

__device__ inline void cvt_hl(float4 a, float4 b, short8_t& h8, short8_t& l8)
{
    const float f[8] = {a.x, a.y, a.z, a.w, b.x, b.y, b.z, b.w};
    #pragma unroll
    for (int j = 0; j < 8; ++j) {
        __hip_bfloat16 h = __float2bfloat16(f[j]);
        h8[j] = __builtin_bit_cast(short, h);
        l8[j] = __builtin_bit_cast(short, __float2bfloat16(f[j] - __bfloat162float(h)));
    }
}

// ---- K0: build split-bf16 W table, k8-major: WH8[k8][e] = bf16hi(W[e][8k8..+7]) ----
__global__ __launch_bounds__(256, 1)
void build_wt(const float* __restrict__ W, short8_t* __restrict__ WH8,
              short8_t* __restrict__ WL8, int* __restrict__ rep_cnt)
{
    const int id = blockIdx.x * 256 + threadIdx.x;   // 64 blocks -> 16384 entries
    if (id == 0) *rep_cnt = 0;
    const int k8 = id & 255, e = id >> 8;
    float4 a = *(const float4*)(W + (long)e * D_MODEL + k8 * 8);
    float4 b = *(const float4*)(W + (long)e * D_MODEL + k8 * 8 + 4);
    short8_t h8, l8;
    cvt_hl(a, b, h8, l8);
    WH8[k8 * NEXP + e] = h8;
    WL8[k8 * NEXP + e] = l8;
}

// ---- K1: barrier-free MFMA GEMM. wave = 16 tokens x 64 experts x K-half ----------
__global__ __launch_bounds__(256, 2)
void router_gemm(const float* __restrict__ x,
                 const short8_t* __restrict__ WH8, const short8_t* __restrict__ WL8,
                 float* __restrict__ p0, float* __restrict__ p1)
{
    const int t = threadIdx.x;
    const int w = t >> 6, l = t & 63;
    const int kh = blockIdx.x & 1;
    const long tokw = (long)(blockIdx.x >> 1) * 64 + w * 16;  // wave's first token
    const int lane16 = l & 15, kq = l >> 4;                   // kq in 0..3
    const long kb0 = (long)kh * KQ;

    const float* xp = x + (tokw + lane16) * D_MODEL + kb0 + kq * 8;
    const short8_t* whp = WH8 + (kb0 / 8 + kq) * NEXP + lane16;
    const short8_t* wlp = WL8 + (kb0 / 8 + kq) * NEXP + lane16;

    f32x4 acc[4];
    #pragma unroll
    for (int nt = 0; nt < 4; ++nt) acc[nt] = (f32x4){0.f, 0.f, 0.f, 0.f};

    float4 xa = *(const float4*)(xp);
    float4 xb = *(const float4*)(xp + 4);

    #pragma unroll 2
    for (int ic = 0; ic < NCHQ; ++ic) {
        short8_t ah, al;
        cvt_hl(xa, xb, ah, al);
        if (ic + 1 < NCHQ) {                       // prefetch next chunk's x
            xa = *(const float4*)(xp + 32 * (ic + 1));
            xb = *(const float4*)(xp + 32 * (ic + 1) + 4);
        }
        const short8_t* wh = whp + (long)ic * 4 * NEXP;
        const short8_t* wl = wlp + (long)ic * 4 * NEXP;
        #pragma unroll
        for (int nt = 0; nt < 4; ++nt) {
            short8_t bh = wh[nt * 16];
            short8_t bl = wl[nt * 16];
            acc[nt] = __builtin_amdgcn_mfma_f32_16x16x32_bf16(ah, bl, acc[nt], 0, 0, 0);
            acc[nt] = __builtin_amdgcn_mfma_f32_16x16x32_bf16(al, bh, acc[nt], 0, 0, 0);
            acc[nt] = __builtin_amdgcn_mfma_f32_16x16x32_bf16(ah, bh, acc[nt], 0, 0, 0);
        }
    }

    // C layout: token = tokw + (l>>4)*4 + r, expert = nt*16 + (l&15)
    float* dst = kh ? p1 : p0;
    #pragma unroll
    for (int nt = 0; nt < 4; ++nt)
        #pragma unroll
        for (int r = 0; r < 4; ++r)
            dst[(tokw + kq * 4 + r) * NEXP + nt * 16 + lane16] = acc[nt][r];
}

// -------- K2: all-register combine: top-3 via shfl merge (verified r8) --------
__global__ __launch_bounds__(256, 1)
void router_combine(const float* __restrict__ p0, const float* __restrict__ p1,
                    float* __restrict__ out, float* __restrict__ cntp,
                    int* __restrict__ rep_cnt, int* __restrict__ rep_list)
{
    __shared__ float4 s_ig[64];      // (i0, i1, g0, g1) per token
    const int t = threadIdx.x;
    const int r = t >> 2, q = t & 3;
    const long tok0 = (long)blockIdx.x * 64;
    const long tok  = tok0 + r;

    float v[16];
    {
        const float4* a4 = (const float4*)(p0 + tok * NEXP) + q * 4;
        const float4* b4 = (const float4*)(p1 + tok * NEXP) + q * 4;
        #pragma unroll
        for (int j = 0; j < 4; ++j) {
            float4 a = a4[j], b = b4[j];
            v[j*4+0] = a.x + b.x; v[j*4+1] = a.y + b.y;
            v[j*4+2] = a.z + b.z; v[j*4+3] = a.w + b.w;
        }
    }

    float b0 = -1e30f, b1 = -1e30f, b2 = -1e30f;
    int i0 = 0, i1 = 0;
    const int ebase = q * 16;
    #pragma unroll
    for (int j = 0; j < 16; ++j) {
        float xv = v[j]; int e = ebase + j;
        if (xv > b0)      { b2 = b1; b1 = b0; i1 = i0; b0 = xv; i0 = e; }
        else if (xv > b1) { b2 = b1; b1 = xv; i1 = e; }
        else if (xv > b2) { b2 = xv; }
    }

    #pragma unroll
    for (int d = 1; d <= 2; d <<= 1) {
        float ob0 = __shfl_xor(b0, d, 64), ob1 = __shfl_xor(b1, d, 64), ob2 = __shfl_xor(b2, d, 64);
        int   oi0 = __shfl_xor(i0, d, 64), oi1 = __shfl_xor(i1, d, 64);
        bool a0w = (b0 > ob0) || (b0 == ob0 && i0 < oi0);
        float nb0 = a0w ? b0 : ob0;  int ni0 = a0w ? i0 : oi0;
        float ca  = a0w ? b1 : ob1;  int cia = a0w ? i1 : oi1;
        float cb  = a0w ? ob0 : b0;  int cib = a0w ? oi0 : i0;
        float wa2 = a0w ? b2 : ob2;
        float lb1 = a0w ? ob1 : b1;
        bool w1 = (ca > cb) || (ca == cb && cia < cib);
        float nb1 = w1 ? ca : cb;  int ni1 = w1 ? cia : cib;
        float nb2 = w1 ? fmaxf(wa2, cb) : fmaxf(ca, lb1);
        b0 = nb0; i0 = ni0; b1 = nb1; i1 = ni1; b2 = nb2;
    }

    float ex = __expf(b1 - b0);
    float g0 = 1.f / (1.f + ex);
    float g1 = ex * g0;

    {
        float* orow = out + tok * NEXP + ebase;
        #pragma unroll
        for (int j4 = 0; j4 < 4; ++j4) {
            float gv[4];
            #pragma unroll
            for (int j = 0; j < 4; ++j) {
                int e = ebase + j4 * 4 + j;
                gv[j] = (e == i0) ? g0 : ((e == i1) ? g1 : 0.f);
            }
            *(float4*)(orow + j4 * 4) = make_float4(gv[0], gv[1], gv[2], gv[3]);
        }
    }

    if (q == 0) {
        out[IDX_OFF + 2 * tok]     = (float)i0;
        out[IDX_OFF + 2 * tok + 1] = (float)i1;
        s_ig[r] = make_float4((float)i0, (float)i1, g0, g1);
        if ((b0 - b1 < TAU) || (b1 - b2 < TAU)) {
            int p = atomicAdd(rep_cnt, 1);
            rep_list[p] = (int)tok;
        }
    }
    __syncthreads();

    if (t < 64) {
        float c = 0.f;
        for (int tt = 0; tt < 64; ++tt) {
            float4 gg = s_ig[tt];
            if ((int)gg.x == t) c += gg.z;
            if ((int)gg.y == t) c += gg.w;
        }
        cntp[blockIdx.x * NEXP + t] = c;
    }
}

// -------- K3: fused tail: block 0 = loss; blocks 1.. = fp64 index repair ------
__global__ __launch_bounds__(256, 1)
void router_tail(const float* __restrict__ x, const float* __restrict__ W,
                 float* __restrict__ out, const float* __restrict__ cntp,
                 const int* __restrict__ rep_cnt, const int* __restrict__ rep_list)
{
    const int t = threadIdx.x;

    if (blockIdx.x == 0) {
        __shared__ double red[4][NEXP];
        const int e = t & 63, p = t >> 6;
        double s = 0.0;
        for (int b = 0; b < 64; ++b)
            s += (double)cntp[(p * 64 + b) * NEXP + e];
        red[p][e] = s;
        __syncthreads();
        if (t == 0) {
            double sc[NEXP], tot = 0.0;
            for (int i = 0; i < NEXP; ++i) {
                sc[i] = red[0][i] + red[1][i] + red[2][i] + red[3][i];
                tot += sc[i];
            }
            double loss = 0.0;
            for (int i = 0; i < NEXP; ++i) {
                double d = sc[i] / tot * (double)NEXP - 1.0;
                loss += d * d;
            }
            out[LOSS_OFF] = (float)(loss / NEXP);
        }
        return;
    }

    __shared__ double red[4][NEXP];
    const int nf = *rep_cnt;
    const int e = t & 63, part = t >> 6;
    for (int i = (int)blockIdx.x - 1; i < nf; i += (int)gridDim.x - 1) {
        const long tok = rep_list[i];
        const float* xr = x + tok * D_MODEL;
        const float* wr = W + (long)e * D_MODEL;
        const int k0 = part * 512;
        double s = 0.0;
        for (int kk = 0; kk < 512; kk += 4) {
            float4 xv = *(const float4*)(xr + k0 + kk);
            float4 wv = *(const float4*)(wr + k0 + kk);
            s = fma((double)xv.x, (double)wv.x, s);
            s = fma((double)xv.y, (double)wv.y, s);
            s = fma((double)xv.z, (double)wv.z, s);
            s = fma((double)xv.w, (double)wv.w, s);
        }
        red[part][e] = s;
        __syncthreads();
        if (t == 0) {
            double best = -1e300, sec = -1e300;
            int bi = 0, si = 0;
            for (int ee = 0; ee < NEXP; ++ee) {
                double vv = red[0][ee] + red[1][ee] + red[2][ee] + red[3][ee];
                if (vv > best)     { sec = best; si = bi; best = vv; bi = ee; }
                else if (vv > sec) { sec = vv; si = ee; }
            }
            out[IDX_OFF + 2 * tok]     = (float)bi;
            out[IDX_OFF + 2 * tok + 1] = (float)si;
        }
        __syncthreads();
    }
}

extern "C" void kernel_launch(void* const* d_in, const int* in_sizes, int n_in,
                              void* d_out, int out_size, void* d_ws, size_t ws_size,
                              hipStream_t stream)
{
    const float* x = (const float*)d_in[0];
    const float* W = (const float*)d_in[1];
    float* out = (float*)d_out;
    float* ws  = (float*)d_ws;         // ~4.9 MB used
    float* p0  = out;                  // kh=0 partial parks in gates region
    float* p1  = ws;
    short8_t* WH8 = (short8_t*)(ws + WS_WH);
    short8_t* WL8 = (short8_t*)(ws + WS_WL);
    float* cntp = ws + WS_CNTP;
    int* rep_cnt  = (int*)(ws + WS_RCNT);
    int* rep_list = (int*)(ws + WS_RLIST);

    build_wt      <<<64, 256, 0, stream>>>(W, WH8, WL8, rep_cnt);
    router_gemm   <<<(TOK_TOTAL / 64) * 2, 256, 0, stream>>>(x, WH8, WL8, p0, p1);
    router_combine<<<TOK_TOTAL / 64, 256, 0, stream>>>(p0, p1, out, cntp, rep_cnt, rep_list);
    router_tail   <<<257, 256, 0, stream>>>(x, W, out, cntp, rep_cnt, rep_list);
}

// Round 11
// 81.599 us; speedup vs baseline: 1.0278x; 1.0261x over previous
//
#include <hip/hip_runtime.h>
#include <hip/hip_bf16.h>
#include <math.h>

#define TOK_TOTAL 16384
#define D_MODEL   2048
#define NEXP      64
#define KQ        1024             // split-K: half of K per wave
#define NCHQ      (KQ / 32)        // 32 chunks of K=32
#define TAU       1e-3f

#define IDX_OFF   (TOK_TOTAL * NEXP)
#define LOSS_OFF  (IDX_OFF + TOK_TOTAL * 2)

// ws layout (floats):
// p1 [16384*64] | WH8 [256KB] | WL8 [256KB] | cntp [256*64] | rep_cnt | rep_list
#define WS_WH     (TOK_TOTAL * NEXP)         // 1048576
#define WS_WL     (WS_WH + 65536)
#define WS_CNTP   (WS_WL + 65536)
#define WS_RCNT   (WS_CNTP + 16384)
#define WS_RLIST  (WS_RCNT + 1)

typedef __attribute__((ext_vector_type(8))) short short8_t;
typedef __attribute__((ext_vector_type(4))) float f32x4;

__device__ inline void cvt_hl(float4 a, float4 b, short8_t& h8, short8_t& l8)
{
    const float f[8] = {a.x, a.y, a.z, a.w, b.x, b.y, b.z, b.w};
    #pragma unroll
    for (int j = 0; j < 8; ++j) {
        __hip_bfloat16 h = __float2bfloat16(f[j]);
        h8[j] = __builtin_bit_cast(short, h);
        l8[j] = __builtin_bit_cast(short, __float2bfloat16(f[j] - __bfloat162float(h)));
    }
}

// ---- K0: build split-bf16 W table, k8-major: WH8[k8][e] = bf16hi(W[e][8k8..+7]) ----
__global__ __launch_bounds__(256, 1)
void build_wt(const float* __restrict__ W, short8_t* __restrict__ WH8,
              short8_t* __restrict__ WL8, int* __restrict__ rep_cnt)
{
    const int id = blockIdx.x * 256 + threadIdx.x;   // 64 blocks -> 16384 entries
    if (id == 0) *rep_cnt = 0;
    const int k8 = id & 255, e = id >> 8;
    float4 a = *(const float4*)(W + (long)e * D_MODEL + k8 * 8);
    float4 b = *(const float4*)(W + (long)e * D_MODEL + k8 * 8 + 4);
    short8_t h8, l8;
    cvt_hl(a, b, h8, l8);
    WH8[k8 * NEXP + e] = h8;
    WL8[k8 * NEXP + e] = l8;
}

// ---- K1: barrier-free MFMA GEMM, 2-deep named register double-buffer ---------
__global__ __launch_bounds__(256, 2)
void router_gemm(const float* __restrict__ x,
                 const short8_t* __restrict__ WH8, const short8_t* __restrict__ WL8,
                 float* __restrict__ p0, float* __restrict__ p1)
{
    const int t = threadIdx.x;
    const int w = t >> 6, l = t & 63;
    const int kh = blockIdx.x & 1;
    const long tokw = (long)(blockIdx.x >> 1) * 64 + w * 16;  // wave's first token
    const int lane16 = l & 15, kq = l >> 4;                   // kq in 0..3
    const long kb0 = (long)kh * KQ;

    const float* xp = x + (tokw + lane16) * D_MODEL + kb0 + kq * 8;
    const short8_t* whp = WH8 + (kb0 / 8 + kq) * NEXP + lane16;
    const short8_t* wlp = WL8 + (kb0 / 8 + kq) * NEXP + lane16;

    f32x4 acc[4];
    #pragma unroll
    for (int nt = 0; nt < 4; ++nt) acc[nt] = (f32x4){0.f, 0.f, 0.f, 0.f};

    // two named register buffers (A/B), each: x(2 float4) + W(8 short8)
    float4 xaA, xbA, xaB, xbB;
    short8_t bhA[4], blA[4], bhB[4], blB[4];

    auto LOADX = [&](int ic, float4& A, float4& B) {
        A = *(const float4*)(xp + 32 * ic);
        B = *(const float4*)(xp + 32 * ic + 4);
    };
    auto LOADW = [&](int ic, short8_t (&H)[4], short8_t (&L)[4]) {
        const short8_t* wh = whp + (long)ic * 4 * NEXP;
        const short8_t* wl = wlp + (long)ic * 4 * NEXP;
        #pragma unroll
        for (int nt = 0; nt < 4; ++nt) { H[nt] = wh[nt * 16]; L[nt] = wl[nt * 16]; }
    };
    auto COMP = [&](const float4& A, const float4& B,
                    short8_t (&H)[4], short8_t (&L)[4]) {
        short8_t ah, al;
        cvt_hl(A, B, ah, al);
        #pragma unroll
        for (int nt = 0; nt < 4; ++nt) {
            acc[nt] = __builtin_amdgcn_mfma_f32_16x16x32_bf16(ah, L[nt], acc[nt], 0, 0, 0);
            acc[nt] = __builtin_amdgcn_mfma_f32_16x16x32_bf16(al, H[nt], acc[nt], 0, 0, 0);
            acc[nt] = __builtin_amdgcn_mfma_f32_16x16x32_bf16(ah, H[nt], acc[nt], 0, 0, 0);
        }
    };

    LOADX(0, xaA, xbA); LOADW(0, bhA, blA);
    for (int ic = 0; ic < NCHQ; ic += 2) {
        // prefetch chunk ic+1 into B, then compute A
        LOADX(ic + 1, xaB, xbB); LOADW(ic + 1, bhB, blB);
        COMP(xaA, xbA, bhA, blA);
        // prefetch chunk ic+2 into A, then compute B
        if (ic + 2 < NCHQ) { LOADX(ic + 2, xaA, xbA); LOADW(ic + 2, bhA, blA); }
        COMP(xaB, xbB, bhB, blB);
    }

    // C layout: token = tokw + kq*4 + r, expert = nt*16 + lane16
    float* dst = kh ? p1 : p0;
    #pragma unroll
    for (int nt = 0; nt < 4; ++nt)
        #pragma unroll
        for (int r = 0; r < 4; ++r)
            dst[(tokw + kq * 4 + r) * NEXP + nt * 16 + lane16] = acc[nt][r];
}

// -------- K2: all-register combine: top-3 via shfl merge (verified r8) --------
__global__ __launch_bounds__(256, 1)
void router_combine(const float* __restrict__ p0, const float* __restrict__ p1,
                    float* __restrict__ out, float* __restrict__ cntp,
                    int* __restrict__ rep_cnt, int* __restrict__ rep_list)
{
    __shared__ float4 s_ig[64];      // (i0, i1, g0, g1) per token
    const int t = threadIdx.x;
    const int r = t >> 2, q = t & 3;
    const long tok0 = (long)blockIdx.x * 64;
    const long tok  = tok0 + r;

    float v[16];
    {
        const float4* a4 = (const float4*)(p0 + tok * NEXP) + q * 4;
        const float4* b4 = (const float4*)(p1 + tok * NEXP) + q * 4;
        #pragma unroll
        for (int j = 0; j < 4; ++j) {
            float4 a = a4[j], b = b4[j];
            v[j*4+0] = a.x + b.x; v[j*4+1] = a.y + b.y;
            v[j*4+2] = a.z + b.z; v[j*4+3] = a.w + b.w;
        }
    }

    float b0 = -1e30f, b1 = -1e30f, b2 = -1e30f;
    int i0 = 0, i1 = 0;
    const int ebase = q * 16;
    #pragma unroll
    for (int j = 0; j < 16; ++j) {
        float xv = v[j]; int e = ebase + j;
        if (xv > b0)      { b2 = b1; b1 = b0; i1 = i0; b0 = xv; i0 = e; }
        else if (xv > b1) { b2 = b1; b1 = xv; i1 = e; }
        else if (xv > b2) { b2 = xv; }
    }

    #pragma unroll
    for (int d = 1; d <= 2; d <<= 1) {
        float ob0 = __shfl_xor(b0, d, 64), ob1 = __shfl_xor(b1, d, 64), ob2 = __shfl_xor(b2, d, 64);
        int   oi0 = __shfl_xor(i0, d, 64), oi1 = __shfl_xor(i1, d, 64);
        bool a0w = (b0 > ob0) || (b0 == ob0 && i0 < oi0);
        float nb0 = a0w ? b0 : ob0;  int ni0 = a0w ? i0 : oi0;
        float ca  = a0w ? b1 : ob1;  int cia = a0w ? i1 : oi1;
        float cb  = a0w ? ob0 : b0;  int cib = a0w ? oi0 : i0;
        float wa2 = a0w ? b2 : ob2;
        float lb1 = a0w ? ob1 : b1;
        bool w1 = (ca > cb) || (ca == cb && cia < cib);
        float nb1 = w1 ? ca : cb;  int ni1 = w1 ? cia : cib;
        float nb2 = w1 ? fmaxf(wa2, cb) : fmaxf(ca, lb1);
        b0 = nb0; i0 = ni0; b1 = nb1; i1 = ni1; b2 = nb2;
    }

    float ex = __expf(b1 - b0);
    float g0 = 1.f / (1.f + ex);
    float g1 = ex * g0;

    {
        float* orow = out + tok * NEXP + ebase;
        #pragma unroll
        for (int j4 = 0; j4 < 4; ++j4) {
            float gv[4];
            #pragma unroll
            for (int j = 0; j < 4; ++j) {
                int e = ebase + j4 * 4 + j;
                gv[j] = (e == i0) ? g0 : ((e == i1) ? g1 : 0.f);
            }
            *(float4*)(orow + j4 * 4) = make_float4(gv[0], gv[1], gv[2], gv[3]);
        }
    }

    if (q == 0) {
        out[IDX_OFF + 2 * tok]     = (float)i0;
        out[IDX_OFF + 2 * tok + 1] = (float)i1;
        s_ig[r] = make_float4((float)i0, (float)i1, g0, g1);
        if ((b0 - b1 < TAU) || (b1 - b2 < TAU)) {
            int p = atomicAdd(rep_cnt, 1);
            rep_list[p] = (int)tok;
        }
    }
    __syncthreads();

    if (t < 64) {
        float c = 0.f;
        for (int tt = 0; tt < 64; ++tt) {
            float4 gg = s_ig[tt];
            if ((int)gg.x == t) c += gg.z;
            if ((int)gg.y == t) c += gg.w;
        }
        cntp[blockIdx.x * NEXP + t] = c;
    }
}

// -------- K3: fused tail: block 0 = loss; blocks 1.. = fp64 index repair ------
__global__ __launch_bounds__(256, 1)
void router_tail(const float* __restrict__ x, const float* __restrict__ W,
                 float* __restrict__ out, const float* __restrict__ cntp,
                 const int* __restrict__ rep_cnt, const int* __restrict__ rep_list)
{
    const int t = threadIdx.x;

    if (blockIdx.x == 0) {
        __shared__ double red[4][NEXP];
        const int e = t & 63, p = t >> 6;
        double s = 0.0;
        for (int b = 0; b < 64; ++b)
            s += (double)cntp[(p * 64 + b) * NEXP + e];
        red[p][e] = s;
        __syncthreads();
        if (t == 0) {
            double sc[NEXP], tot = 0.0;
            for (int i = 0; i < NEXP; ++i) {
                sc[i] = red[0][i] + red[1][i] + red[2][i] + red[3][i];
                tot += sc[i];
            }
            double loss = 0.0;
            for (int i = 0; i < NEXP; ++i) {
                double d = sc[i] / tot * (double)NEXP - 1.0;
                loss += d * d;
            }
            out[LOSS_OFF] = (float)(loss / NEXP);
        }
        return;
    }

    __shared__ double red[4][NEXP];
    const int nf = *rep_cnt;
    const int e = t & 63, part = t >> 6;
    for (int i = (int)blockIdx.x - 1; i < nf; i += (int)gridDim.x - 1) {
        const long tok = rep_list[i];
        const float* xr = x + tok * D_MODEL;
        const float* wr = W + (long)e * D_MODEL;
        const int k0 = part * 512;
        double s = 0.0;
        for (int kk = 0; kk < 512; kk += 4) {
            float4 xv = *(const float4*)(xr + k0 + kk);
            float4 wv = *(const float4*)(wr + k0 + kk);
            s = fma((double)xv.x, (double)wv.x, s);
            s = fma((double)xv.y, (double)wv.y, s);
            s = fma((double)xv.z, (double)wv.z, s);
            s = fma((double)xv.w, (double)wv.w, s);
        }
        red[part][e] = s;
        __syncthreads();
        if (t == 0) {
            double best = -1e300, sec = -1e300;
            int bi = 0, si = 0;
            for (int ee = 0; ee < NEXP; ++ee) {
                double vv = red[0][ee] + red[1][ee] + red[2][ee] + red[3][ee];
                if (vv > best)     { sec = best; si = bi; best = vv; bi = ee; }
                else if (vv > sec) { sec = vv; si = ee; }
            }
            out[IDX_OFF + 2 * tok]     = (float)bi;
            out[IDX_OFF + 2 * tok + 1] = (float)si;
        }
        __syncthreads();
    }
}

extern "C" void kernel_launch(void* const* d_in, const int* in_sizes, int n_in,
                              void* d_out, int out_size, void* d_ws, size_t ws_size,
                              hipStream_t stream)
{
    const float* x = (const float*)d_in[0];
    const float* W = (const float*)d_in[1];
    float* out = (float*)d_out;
    float* ws  = (float*)d_ws;         // ~4.9 MB used
    float* p0  = out;                  // kh=0 partial parks in gates region
    float* p1  = ws;
    short8_t* WH8 = (short8_t*)(ws + WS_WH);
    short8_t* WL8 = (short8_t*)(ws + WS_WL);
    float* cntp = ws + WS_CNTP;
    int* rep_cnt  = (int*)(ws + WS_RCNT);
    int* rep_list = (int*)(ws + WS_RLIST);

    build_wt      <<<64, 256, 0, stream>>>(W, WH8, WL8, rep_cnt);
    router_gemm   <<<(TOK_TOTAL / 64) * 2, 256, 0, stream>>>(x, WH8, WL8, p0, p1);
    router_combine<<<TOK_TOTAL / 64, 256, 0, stream>>>(p0, p1, out, cntp, rep_cnt, rep_list);
    router_tail   <<<257, 256, 0, stream>>>(x, W, out, cntp, rep_cnt, rep_list);
}